// Round 8
// baseline (96.552 us; speedup 1.0000x reference)
//
#include <hip/hip_runtime.h>

#define N_NODES 50000
#define N_EDGES 800000
#define D_FEAT 128
#define HEADS 8
#define HEAD_DIM 16
#define ELL_CAP 64
#define NBKT 196            // dst>>8 in [0,196)
#define BKT_CAP 5120        // mean 4096, sigma ~64 -> +16 sigma
#define OVF_CAP 65536
#define NB_COLS 144         // 128 h-cols + 8 a_src + 8 a_dst
#define PREP_BLKS 72        // 144*128/256
#define NGEMM ((N_NODES + 63) / 64)   // 782

typedef __attribute__((ext_vector_type(8))) short bf16x8;
typedef __attribute__((ext_vector_type(4))) float f32x4;

static __device__ __forceinline__ ushort f2bf(float f) {
  uint u = __float_as_uint(f);
  u += 0x7fffu + ((u >> 16) & 1u);    // RNE
  return (ushort)(u >> 16);
}
static __device__ __forceinline__ float bf2f_lo(uint u) { return __uint_as_float(u << 16); }
static __device__ __forceinline__ float bf2f_hi(uint u) { return __uint_as_float(u & 0xffff0000u); }

static constexpr size_t alignup(size_t v) { return (v + 255) & ~255ull; }
// ---------------- workspace layout (bytes) ----------------
static constexpr size_t OFF_HB   = 0;                                           // [N,128] bf16
static constexpr size_t OFF_ASRC = alignup(OFF_HB + (size_t)N_NODES * 128 * 2); // [N,8] f32
static constexpr size_t OFF_ADST = alignup(OFF_ASRC + (size_t)N_NODES * 8 * 4); // [N,8] f32
static constexpr size_t OFF_CNT  = alignup(OFF_ADST + (size_t)N_NODES * 8 * 4); // [N] i32
static constexpr size_t OFF_GCNT = alignup(OFF_CNT + (size_t)N_NODES * 4);      // [NBKT] i32
static constexpr size_t OFF_OVFC = OFF_GCNT + (size_t)NBKT * 4;                 // [1] i32 (contig w/ gcnt for memset)
static constexpr size_t OFF_ELL  = alignup(OFF_OVFC + 4);                       // [N*64] u16
static constexpr size_t OFF_BKT  = alignup(OFF_ELL + (size_t)N_NODES * ELL_CAP * 2); // [NBKT*BKT_CAP] u32
static constexpr size_t OFF_OVF  = alignup(OFF_BKT + (size_t)NBKT * BKT_CAP * 4);    // [OVF_CAP] int2
static constexpr size_t OFF_WT   = alignup(OFF_OVF + (size_t)OVF_CAP * 8);      // [144*128] bf16 swizzled

// ---------------- pass 1 + prep: bin edges / build Wt (merged grid) ----------
__global__ __launch_bounds__(256) void k_binprep(const int* __restrict__ src,
                                                 const int* __restrict__ dst,
                                                 int* __restrict__ gcnt,
                                                 uint* __restrict__ bkt,
                                                 int* __restrict__ ovfc,
                                                 int2* __restrict__ ovf,
                                                 const float* __restrict__ W,
                                                 const float* __restrict__ att_src,
                                                 const float* __restrict__ att_dst,
                                                 char* __restrict__ Wt, int E) {
  if (blockIdx.x >= NBKT) {
    int t = (blockIdx.x - NBKT) * 256 + threadIdx.x;   // 0..18431
    int n = t >> 7, k = t & 127;
    float v;
    if (n < 128) {
      v = W[k * 128 + n];
    } else {
      int j = n - 128, jj = j & 7;
      const float* att = (j < 8) ? att_src : att_dst;
      v = 0.f;
#pragma unroll
      for (int c = 0; c < 16; ++c) v += W[k * 128 + jj * 16 + c] * att[jj * 16 + c];
    }
    int off = (n * 256 + k * 2) ^ ((n & 7) << 4);
    *(ushort*)(Wt + off) = f2bf(v);
    return;
  }
  __shared__ int hist[NBKT];
  __shared__ int base[NBKT];
  const int t = threadIdx.x;
  const int e0 = blockIdx.x * 4096;
  for (int i = t; i < NBKT; i += 256) hist[i] = 0;
  __syncthreads();

  uint pk[16];
  int bk[16];
#pragma unroll
  for (int j = 0; j < 4; ++j) {
    int e = e0 + j * 1024 + t * 4;
    if (e < E) {                       // E%4==0: quad fully valid
      int4 d4 = *(const int4*)(dst + e);
      int4 s4 = *(const int4*)(src + e);
      bk[j * 4 + 0] = d4.x >> 8; pk[j * 4 + 0] = ((uint)(d4.x & 255) << 16) | (uint)s4.x;
      bk[j * 4 + 1] = d4.y >> 8; pk[j * 4 + 1] = ((uint)(d4.y & 255) << 16) | (uint)s4.y;
      bk[j * 4 + 2] = d4.z >> 8; pk[j * 4 + 2] = ((uint)(d4.z & 255) << 16) | (uint)s4.z;
      bk[j * 4 + 3] = d4.w >> 8; pk[j * 4 + 3] = ((uint)(d4.w & 255) << 16) | (uint)s4.w;
      atomicAdd(&hist[bk[j * 4 + 0]], 1);
      atomicAdd(&hist[bk[j * 4 + 1]], 1);
      atomicAdd(&hist[bk[j * 4 + 2]], 1);
      atomicAdd(&hist[bk[j * 4 + 3]], 1);
    } else {
      bk[j * 4 + 0] = -1; bk[j * 4 + 1] = -1; bk[j * 4 + 2] = -1; bk[j * 4 + 3] = -1;
      pk[j * 4 + 0] = 0;  pk[j * 4 + 1] = 0;  pk[j * 4 + 2] = 0;  pk[j * 4 + 3] = 0;
    }
  }
  __syncthreads();
  for (int i = t; i < NBKT; i += 256) {
    base[i] = atomicAdd(&gcnt[i], hist[i]);
    hist[i] = 0;
  }
  __syncthreads();
#pragma unroll
  for (int j = 0; j < 16; ++j) {
    if (bk[j] >= 0) {
      int pos = atomicAdd(&hist[bk[j]], 1);
      int gp = base[bk[j]] + pos;
      if (gp < BKT_CAP) {
        bkt[(size_t)bk[j] * BKT_CAP + gp] = pk[j];
      } else {
        int q = atomicAdd(ovfc, 1);
        if (q < OVF_CAP) ovf[q] = make_int2((bk[j] << 8) | (int)(pk[j] >> 16), (int)(pk[j] & 0xffffu));
      }
    }
  }
}

// ---------------- mega-kernel: blocks [0,NGEMM)=MFMA GEMM, rest = ELL build --
// Independent work fused into one dispatch so they overlap on the device.
__global__ __launch_bounds__(256) void k_gemmbuild(const float* __restrict__ x,
                                                   const char* __restrict__ Wt,
                                                   ushort* __restrict__ hb,
                                                   float* __restrict__ a_src,
                                                   float* __restrict__ a_dst,
                                                   const uint* __restrict__ bkt,
                                                   const int* __restrict__ gcnt,
                                                   int* __restrict__ cnt,
                                                   ushort* __restrict__ ell,
                                                   int* __restrict__ ovfc,
                                                   int2* __restrict__ ovf, int N) {
  __shared__ union SM {
    ushort wl[NB_COLS * 128];                       // 36 KB (gemm branch)
    struct { ushort lell[256 * ELL_CAP]; int lcnt[256]; } b;  // 33 KB (build)
  } sm;
  const int tid = threadIdx.x;

  if (blockIdx.x < NGEMM) {
    // ---------------- GEMM branch ----------------
    const uint4* Wg4 = (const uint4*)Wt;
    uint4* Wl4 = (uint4*)sm.wl;
#pragma unroll
    for (int i = 0; i < 9; ++i) Wl4[tid + i * 256] = Wg4[tid + i * 256];
    __syncthreads();

    const int w = tid >> 6, l = tid & 63;
    const int R = blockIdx.x * 64 + w * 16;
    const int m = l & 15, kg = l >> 4;
    const char* Wlb = (const char*)sm.wl;

    f32x4 acc[9];
#pragma unroll
    for (int j = 0; j < 9; ++j) acc[j] = (f32x4){0.f, 0.f, 0.f, 0.f};

    const int row = R + m;
    const bool valid = row < N;
    const float4* xr = (const float4*)(x + (size_t)(valid ? row : 0) * 128);

#pragma unroll
    for (int kt = 0; kt < 4; ++kt) {
      const int k0 = kt * 32 + kg * 8;
      float4 xa = valid ? xr[k0 >> 2] : make_float4(0.f, 0.f, 0.f, 0.f);
      float4 xb = valid ? xr[(k0 >> 2) + 1] : make_float4(0.f, 0.f, 0.f, 0.f);
      bf16x8 a;
      a[0] = (short)f2bf(xa.x); a[1] = (short)f2bf(xa.y);
      a[2] = (short)f2bf(xa.z); a[3] = (short)f2bf(xa.w);
      a[4] = (short)f2bf(xb.x); a[5] = (short)f2bf(xb.y);
      a[6] = (short)f2bf(xb.z); a[7] = (short)f2bf(xb.w);
#pragma unroll
      for (int j = 0; j < 9; ++j) {
        int n = j * 16 + m;
        int off = (n * 256 + k0 * 2) ^ ((n & 7) << 4);
        bf16x8 b = *(const bf16x8*)(Wlb + off);
        acc[j] = __builtin_amdgcn_mfma_f32_16x16x32_bf16(a, b, acc[j], 0, 0, 0);
      }
    }
    // C layout: col = j*16 + m, row = R + kg*4 + r
#pragma unroll
    for (int j = 0; j < 8; ++j) {
      int col = j * 16 + m;
#pragma unroll
      for (int r = 0; r < 4; ++r) {
        int rr = R + kg * 4 + r;
        if (rr < N) hb[(size_t)rr * 128 + col] = f2bf(acc[j][r]);
      }
    }
#pragma unroll
    for (int r = 0; r < 4; ++r) {
      int rr = R + kg * 4 + r;
      if (rr < N) {
        if (m < 8) a_src[rr * 8 + m] = acc[8][r];
        else       a_dst[rr * 8 + (m - 8)] = acc[8][r];
      }
    }
    return;
  }

  // ---------------- ELL build branch ----------------
  const int b = blockIdx.x - NGEMM;
  const int t = tid;
  sm.b.lcnt[t] = 0;
  __syncthreads();

  const int nb = min(gcnt[b], BKT_CAP);
  for (int i = t; i < nb; i += 256) {
    uint pk = bkt[(size_t)b * BKT_CAP + i];
    int dl = (int)(pk >> 16);
    int pos = atomicAdd(&sm.b.lcnt[dl], 1);
    if (pos < ELL_CAP) {
      sm.b.lell[dl * ELL_CAP + pos] = (ushort)(pk & 0xffffu);
    } else {
      int q = atomicAdd(ovfc, 1);
      if (q < OVF_CAP) ovf[q] = make_int2((b << 8) | dl, (int)(pk & 0xffffu));
    }
  }
  __syncthreads();

  const int n0 = b << 8;
  if (n0 + t < N_NODES) cnt[n0 + t] = sm.b.lcnt[t];
  const uint4* l4 = (const uint4*)sm.b.lell;
  uint4* g4 = (uint4*)(ell + (size_t)n0 * ELL_CAP);
  for (int i = t; i < 2048; i += 256) {       // 256 nodes * 128B = 32KB
    if (n0 + (i >> 3) < N_NODES) g4[i] = l4[i];
  }
}

// ---------------- gather + softmax aggregate + residual + LN ----------------
template<bool CLAMP>
static __device__ __forceinline__ void gat_block(const uint* __restrict__ hu,
                                                 const float* __restrict__ a_src,
                                                 uint4 qi, int e, int deg,
                                                 uint hd, uint lane, float adst,
                                                 float& acc0, float& acc1, float& den) {
  uint s[8];
  s[0] = qi.x & 0xffffu; s[1] = qi.x >> 16;
  s[2] = qi.y & 0xffffu; s[3] = qi.y >> 16;
  s[4] = qi.z & 0xffffu; s[5] = qi.z >> 16;
  s[6] = qi.w & 0xffffu; s[7] = qi.w >> 16;
  float A[8]; uint u[8];
#pragma unroll
  for (int k = 0; k < 8; ++k) {
    if (CLAMP && e + k >= deg) s[k] = 0;
    A[k] = a_src[s[k] * 8u + hd];           // 32-bit offset, SADDR form
    u[k] = hu[(s[k] << 6) | lane];
  }
#pragma unroll
  for (int k = 0; k < 8; ++k) {
    float a = A[k] + adst;
    a = a > 0.f ? a : 0.2f * a;             // LeakyReLU(0.2)
    float p = __expf(a);
    if (CLAMP && e + k >= deg) p = 0.f;
    acc0 = fmaf(p, bf2f_lo(u[k]), acc0);
    acc1 = fmaf(p, bf2f_hi(u[k]), acc1);
    den += p;
  }
}

__global__ __launch_bounds__(256) void k_gat(const ushort* __restrict__ hb,
                                             const float* __restrict__ a_src,
                                             const float* __restrict__ a_dst,
                                             const int* __restrict__ cnt,
                                             const ushort* __restrict__ ell,
                                             const int* __restrict__ ovfc,
                                             const int2* __restrict__ ovf,
                                             const float* __restrict__ x,
                                             const float* __restrict__ bias,
                                             const float* __restrict__ gamma,
                                             const float* __restrict__ beta,
                                             float* __restrict__ out, int N) {
  const int wid = threadIdx.x >> 6;
  const uint lane = threadIdx.x & 63;
  const int n = blockIdx.x * 4 + wid;
  if (n >= N) return;
  const uint hd = lane >> 3;
  const float adst = a_dst[n * 8 + hd];
  const int degt = cnt[n];
  const int deg = degt < ELL_CAP ? degt : ELL_CAP;
  const uint* hu = (const uint*)hb;
  const uint4* rq = (const uint4*)(ell + (size_t)n * ELL_CAP);

  float acc0 = 0.f, acc1 = 0.f, den = 0.f;
  const int nblk = (deg + 7) >> 3;
  if (nblk > 0) {
    uint4 qi = rq[0];                        // software pipeline: 1-ahead idx load
    for (int b = 0; b < nblk; ++b) {
      uint4 qn = (b + 1 < nblk) ? rq[b + 1] : qi;
      if ((b == nblk - 1) && (deg & 7))
        gat_block<true>(hu, a_src, qi, b * 8, deg, hd, lane, adst, acc0, acc1, den);
      else
        gat_block<false>(hu, a_src, qi, b * 8, deg, hd, lane, adst, acc0, acc1, den);
      qi = qn;
    }
  }
  {
    int novf = *ovfc;                        // ~always 0; one broadcast load
    if (novf > 0) {
      novf = novf < OVF_CAP ? novf : OVF_CAP;
      for (int q = 0; q < novf; ++q) {
        int2 pr = ovf[q];
        if (pr.x == n) {
          uint s = (uint)pr.y;
          float a = a_src[s * 8u + hd] + adst;
          a = a > 0.f ? a : 0.2f * a;
          float p = __expf(a);
          uint u = hu[(s << 6) | lane];
          acc0 = fmaf(p, bf2f_lo(u), acc0);
          acc1 = fmaf(p, bf2f_hi(u), acc1);
          den += p;
        }
      }
    }
  }
  float r = 1.0f / (den + 1e-16f);
  float2 bv = ((const float2*)bias)[lane];
  float2 xv = ((const float2*)x)[(size_t)n * 64 + lane];
  float o0 = fmaf(acc0, r, bv.x + xv.x);
  float o1 = fmaf(acc1, r, bv.y + xv.y);

  float s1 = o0 + o1;
  float s2 = o0 * o0 + o1 * o1;
#pragma unroll
  for (int off = 32; off > 0; off >>= 1) {
    s1 += __shfl_xor(s1, off);
    s2 += __shfl_xor(s2, off);
  }
  float mean = s1 * (1.0f / 128.0f);
  float var = s2 * (1.0f / 128.0f) - mean * mean;
  var = var < 0.f ? 0.f : var;
  float rstd = rsqrtf(var + 1e-5f);
  float2 gv = ((const float2*)gamma)[lane];
  float2 bt = ((const float2*)beta)[lane];
  float2 ov;
  ov.x = (o0 - mean) * rstd * gv.x + bt.x;
  ov.y = (o1 - mean) * rstd * gv.y + bt.y;
  ((float2*)out)[(size_t)n * 64 + lane] = ov;
}

// ---------------- launch ----------------
extern "C" void kernel_launch(void* const* d_in, const int* in_sizes, int n_in,
                              void* d_out, int out_size, void* d_ws, size_t ws_size,
                              hipStream_t stream) {
  const float* x       = (const float*)d_in[0];
  const int*   ei      = (const int*)d_in[1];
  const float* W       = (const float*)d_in[2];
  const float* att_src = (const float*)d_in[3];
  const float* att_dst = (const float*)d_in[4];
  const float* bias    = (const float*)d_in[5];
  const float* gamma   = (const float*)d_in[6];
  const float* beta    = (const float*)d_in[7];
  float* out = (float*)d_out;

  char* ws = (char*)d_ws;
  ushort* hb   = (ushort*)(ws + OFF_HB);
  float* a_src = (float*)(ws + OFF_ASRC);
  float* a_dst = (float*)(ws + OFF_ADST);
  int* cnt   = (int*)(ws + OFF_CNT);
  int* gcnt  = (int*)(ws + OFF_GCNT);
  int* ovfc  = (int*)(ws + OFF_OVFC);
  ushort* ell = (ushort*)(ws + OFF_ELL);
  uint* bkt  = (uint*)(ws + OFF_BKT);
  int2* ovf  = (int2*)(ws + OFF_OVF);
  char* Wt   = ws + OFF_WT;

  const int* srcIdx = ei;
  const int* dstIdx = ei + N_EDGES;

  hipMemsetAsync(ws + OFF_GCNT, 0, (NBKT + 1) * 4, stream);  // gcnt + ovfc
  k_binprep<<<NBKT + PREP_BLKS, 256, 0, stream>>>(srcIdx, dstIdx, gcnt, bkt, ovfc, ovf,
                                                  W, att_src, att_dst, Wt, N_EDGES);
  k_gemmbuild<<<NGEMM + NBKT, 256, 0, stream>>>(x, Wt, hb, a_src, a_dst,
                                                bkt, gcnt, cnt, ell, ovfc, ovf, N_NODES);
  k_gat<<<(N_NODES + 3) / 4, 256, 0, stream>>>(hb, a_src, a_dst, cnt, ell, ovfc, ovf, x, bias, gamma, beta, out, N_NODES);
}

// Round 9
// 77.122 us; speedup vs baseline: 1.2519x; 1.2519x over previous
//
#include <hip/hip_runtime.h>

#define N_NODES 50000
#define N_EDGES 800000
#define D_FEAT 128
#define HEADS 8
#define HEAD_DIM 16
#define ELL_CAP 64
#define NBKT 196            // dst>>8 in [0,196)
#define BKT_CAP 5120        // mean 4096, sigma ~64 -> +16 sigma
#define OVF_CAP 65536
#define NB_COLS 144         // 128 h-cols + 8 a_src + 8 a_dst
#define PREP_BLKS 72        // 144*128/256
#define NGEMM ((N_NODES + 63) / 64)   // 782

typedef __attribute__((ext_vector_type(8))) short bf16x8;
typedef __attribute__((ext_vector_type(4))) float f32x4;

static __device__ __forceinline__ ushort f2bf(float f) {
  uint u = __float_as_uint(f);
  u += 0x7fffu + ((u >> 16) & 1u);    // RNE
  return (ushort)(u >> 16);
}
static __device__ __forceinline__ float bf2f_lo(uint u) { return __uint_as_float(u << 16); }
static __device__ __forceinline__ float bf2f_hi(uint u) { return __uint_as_float(u & 0xffff0000u); }

static constexpr size_t alignup(size_t v) { return (v + 255) & ~255ull; }
// ---------------- workspace layout (bytes) ----------------
static constexpr size_t OFF_HB   = 0;                                           // [N,128] bf16
static constexpr size_t OFF_ASRC = alignup(OFF_HB + (size_t)N_NODES * 128 * 2); // [N,8] f32
static constexpr size_t OFF_ADST = alignup(OFF_ASRC + (size_t)N_NODES * 8 * 4); // [N,8] f32
static constexpr size_t OFF_CNT  = alignup(OFF_ADST + (size_t)N_NODES * 8 * 4); // [N] i32
static constexpr size_t OFF_GCNT = alignup(OFF_CNT + (size_t)N_NODES * 4);      // [NBKT] i32
static constexpr size_t OFF_OVFC = OFF_GCNT + (size_t)NBKT * 4;                 // [1] i32 (contig w/ gcnt for memset)
static constexpr size_t OFF_ELL  = alignup(OFF_OVFC + 4);                       // [N*64] u16
static constexpr size_t OFF_BKT  = alignup(OFF_ELL + (size_t)N_NODES * ELL_CAP * 2); // [NBKT*BKT_CAP] u32
static constexpr size_t OFF_OVF  = alignup(OFF_BKT + (size_t)NBKT * BKT_CAP * 4);    // [OVF_CAP] int2
static constexpr size_t OFF_WT   = alignup(OFF_OVF + (size_t)OVF_CAP * 8);      // [144*128] bf16 swizzled

// ---------------- pass 1 + prep: bin edges / build Wt (merged grid) ----------
__global__ __launch_bounds__(256) void k_binprep(const int* __restrict__ src,
                                                 const int* __restrict__ dst,
                                                 int* __restrict__ gcnt,
                                                 uint* __restrict__ bkt,
                                                 int* __restrict__ ovfc,
                                                 int2* __restrict__ ovf,
                                                 const float* __restrict__ W,
                                                 const float* __restrict__ att_src,
                                                 const float* __restrict__ att_dst,
                                                 char* __restrict__ Wt, int E) {
  if (blockIdx.x >= NBKT) {
    int t = (blockIdx.x - NBKT) * 256 + threadIdx.x;   // 0..18431
    int n = t >> 7, k = t & 127;
    float v;
    if (n < 128) {
      v = W[k * 128 + n];
    } else {
      int j = n - 128, jj = j & 7;
      const float* att = (j < 8) ? att_src : att_dst;
      v = 0.f;
#pragma unroll
      for (int c = 0; c < 16; ++c) v += W[k * 128 + jj * 16 + c] * att[jj * 16 + c];
    }
    int off = (n * 256 + k * 2) ^ ((n & 7) << 4);
    *(ushort*)(Wt + off) = f2bf(v);
    return;
  }
  __shared__ int hist[NBKT];
  __shared__ int base[NBKT];
  const int t = threadIdx.x;
  const int e0 = blockIdx.x * 4096;
  for (int i = t; i < NBKT; i += 256) hist[i] = 0;
  __syncthreads();

  uint pk[16];
  int bk[16];
#pragma unroll
  for (int j = 0; j < 4; ++j) {
    int e = e0 + j * 1024 + t * 4;
    if (e < E) {                       // E%4==0: quad fully valid
      int4 d4 = *(const int4*)(dst + e);
      int4 s4 = *(const int4*)(src + e);
      bk[j * 4 + 0] = d4.x >> 8; pk[j * 4 + 0] = ((uint)(d4.x & 255) << 16) | (uint)s4.x;
      bk[j * 4 + 1] = d4.y >> 8; pk[j * 4 + 1] = ((uint)(d4.y & 255) << 16) | (uint)s4.y;
      bk[j * 4 + 2] = d4.z >> 8; pk[j * 4 + 2] = ((uint)(d4.z & 255) << 16) | (uint)s4.z;
      bk[j * 4 + 3] = d4.w >> 8; pk[j * 4 + 3] = ((uint)(d4.w & 255) << 16) | (uint)s4.w;
      atomicAdd(&hist[bk[j * 4 + 0]], 1);
      atomicAdd(&hist[bk[j * 4 + 1]], 1);
      atomicAdd(&hist[bk[j * 4 + 2]], 1);
      atomicAdd(&hist[bk[j * 4 + 3]], 1);
    } else {
      bk[j * 4 + 0] = -1; bk[j * 4 + 1] = -1; bk[j * 4 + 2] = -1; bk[j * 4 + 3] = -1;
      pk[j * 4 + 0] = 0;  pk[j * 4 + 1] = 0;  pk[j * 4 + 2] = 0;  pk[j * 4 + 3] = 0;
    }
  }
  __syncthreads();
  for (int i = t; i < NBKT; i += 256) {
    base[i] = atomicAdd(&gcnt[i], hist[i]);
    hist[i] = 0;
  }
  __syncthreads();
#pragma unroll
  for (int j = 0; j < 16; ++j) {
    if (bk[j] >= 0) {
      int pos = atomicAdd(&hist[bk[j]], 1);
      int gp = base[bk[j]] + pos;
      if (gp < BKT_CAP) {
        bkt[(size_t)bk[j] * BKT_CAP + gp] = pk[j];
      } else {
        int q = atomicAdd(ovfc, 1);
        if (q < OVF_CAP) ovf[q] = make_int2((bk[j] << 8) | (int)(pk[j] >> 16), (int)(pk[j] & 0xffffu));
      }
    }
  }
}

// ---------------- mega-kernel: blocks [0,NGEMM)=MFMA GEMM, rest = ELL build --
__global__ __launch_bounds__(256) void k_gemmbuild(const float* __restrict__ x,
                                                   const char* __restrict__ Wt,
                                                   ushort* __restrict__ hb,
                                                   float* __restrict__ a_src,
                                                   float* __restrict__ a_dst,
                                                   const uint* __restrict__ bkt,
                                                   const int* __restrict__ gcnt,
                                                   int* __restrict__ cnt,
                                                   ushort* __restrict__ ell,
                                                   int* __restrict__ ovfc,
                                                   int2* __restrict__ ovf, int N) {
  __shared__ union SM {
    ushort wl[NB_COLS * 128];                       // 36 KB (gemm branch)
    struct { ushort lell[256 * ELL_CAP]; int lcnt[256]; } b;  // 33 KB (build)
  } sm;
  const int tid = threadIdx.x;

  if (blockIdx.x < NGEMM) {
    // ---------------- GEMM branch ----------------
    const uint4* Wg4 = (const uint4*)Wt;
    uint4* Wl4 = (uint4*)sm.wl;
#pragma unroll
    for (int i = 0; i < 9; ++i) Wl4[tid + i * 256] = Wg4[tid + i * 256];
    __syncthreads();

    const int w = tid >> 6, l = tid & 63;
    const int R = blockIdx.x * 64 + w * 16;
    const int m = l & 15, kg = l >> 4;
    const char* Wlb = (const char*)sm.wl;

    f32x4 acc[9];
#pragma unroll
    for (int j = 0; j < 9; ++j) acc[j] = (f32x4){0.f, 0.f, 0.f, 0.f};

    const int row = R + m;
    const bool valid = row < N;
    const float4* xr = (const float4*)(x + (size_t)(valid ? row : 0) * 128);

#pragma unroll
    for (int kt = 0; kt < 4; ++kt) {
      const int k0 = kt * 32 + kg * 8;
      float4 xa = valid ? xr[k0 >> 2] : make_float4(0.f, 0.f, 0.f, 0.f);
      float4 xb = valid ? xr[(k0 >> 2) + 1] : make_float4(0.f, 0.f, 0.f, 0.f);
      bf16x8 a;
      a[0] = (short)f2bf(xa.x); a[1] = (short)f2bf(xa.y);
      a[2] = (short)f2bf(xa.z); a[3] = (short)f2bf(xa.w);
      a[4] = (short)f2bf(xb.x); a[5] = (short)f2bf(xb.y);
      a[6] = (short)f2bf(xb.z); a[7] = (short)f2bf(xb.w);
#pragma unroll
      for (int j = 0; j < 9; ++j) {
        int n = j * 16 + m;
        int off = (n * 256 + k0 * 2) ^ ((n & 7) << 4);
        bf16x8 b = *(const bf16x8*)(Wlb + off);
        acc[j] = __builtin_amdgcn_mfma_f32_16x16x32_bf16(a, b, acc[j], 0, 0, 0);
      }
    }
    // C layout: col = j*16 + m, row = R + kg*4 + r
#pragma unroll
    for (int j = 0; j < 8; ++j) {
      int col = j * 16 + m;
#pragma unroll
      for (int r = 0; r < 4; ++r) {
        int rr = R + kg * 4 + r;
        if (rr < N) hb[(size_t)rr * 128 + col] = f2bf(acc[j][r]);
      }
    }
#pragma unroll
    for (int r = 0; r < 4; ++r) {
      int rr = R + kg * 4 + r;
      if (rr < N) {
        if (m < 8) a_src[rr * 8 + m] = acc[8][r];
        else       a_dst[rr * 8 + (m - 8)] = acc[8][r];
      }
    }
    return;
  }

  // ---------------- ELL build branch ----------------
  const int b = blockIdx.x - NGEMM;
  const int t = tid;
  sm.b.lcnt[t] = 0;
  __syncthreads();

  const int nb = min(gcnt[b], BKT_CAP);
  for (int i = t; i < nb; i += 256) {
    uint pk = bkt[(size_t)b * BKT_CAP + i];
    int dl = (int)(pk >> 16);
    int pos = atomicAdd(&sm.b.lcnt[dl], 1);
    if (pos < ELL_CAP) {
      sm.b.lell[dl * ELL_CAP + pos] = (ushort)(pk & 0xffffu);
    } else {
      int q = atomicAdd(ovfc, 1);
      if (q < OVF_CAP) ovf[q] = make_int2((b << 8) | dl, (int)(pk & 0xffffu));
    }
  }
  __syncthreads();

  const int n0 = b << 8;
  if (n0 + t < N_NODES) cnt[n0 + t] = sm.b.lcnt[t];
  const uint4* l4 = (const uint4*)sm.b.lell;
  uint4* g4 = (uint4*)(ell + (size_t)n0 * ELL_CAP);
  for (int i = t; i < 2048; i += 256) {       // 256 nodes * 128B = 32KB
    if (n0 + (i >> 3) < N_NODES) g4[i] = l4[i];
  }
}

// ---------------- gather + softmax aggregate + residual + LN ----------------
// R7 structure exactly (no idx prefetch -- R8's pipeline caused scratch spill)
template<bool CLAMP>
static __device__ __forceinline__ void gat_block(const uint* __restrict__ hu,
                                                 const float* __restrict__ a_src,
                                                 const ushort* __restrict__ row,
                                                 int e, int deg, uint hd, uint lane,
                                                 float adst, float& acc0, float& acc1,
                                                 float& den) {
  uint4 qi = *(const uint4*)(row + e);      // 8 u16 indices, wave-uniform 16B
  uint s[8];
  s[0] = qi.x & 0xffffu; s[1] = qi.x >> 16;
  s[2] = qi.y & 0xffffu; s[3] = qi.y >> 16;
  s[4] = qi.z & 0xffffu; s[5] = qi.z >> 16;
  s[6] = qi.w & 0xffffu; s[7] = qi.w >> 16;
  float A[8]; uint u[8];
#pragma unroll
  for (int k = 0; k < 8; ++k) {
    if (CLAMP && e + k >= deg) s[k] = 0;
    A[k] = a_src[s[k] * 8u + hd];           // 32-bit offset, SADDR form
    u[k] = hu[(s[k] << 6) | lane];
  }
#pragma unroll
  for (int k = 0; k < 8; ++k) {
    float a = A[k] + adst;
    a = a > 0.f ? a : 0.2f * a;             // LeakyReLU(0.2)
    float p = __expf(a);
    if (CLAMP && e + k >= deg) p = 0.f;
    acc0 = fmaf(p, bf2f_lo(u[k]), acc0);
    acc1 = fmaf(p, bf2f_hi(u[k]), acc1);
    den += p;
  }
}

__global__ __launch_bounds__(256) void k_gat(const ushort* __restrict__ hb,
                                             const float* __restrict__ a_src,
                                             const float* __restrict__ a_dst,
                                             const int* __restrict__ cnt,
                                             const ushort* __restrict__ ell,
                                             const int* __restrict__ ovfc,
                                             const int2* __restrict__ ovf,
                                             const float* __restrict__ x,
                                             const float* __restrict__ bias,
                                             const float* __restrict__ gamma,
                                             const float* __restrict__ beta,
                                             float* __restrict__ out, int N) {
  const int wid = threadIdx.x >> 6;
  const uint lane = threadIdx.x & 63;
  const int n = blockIdx.x * 4 + wid;
  if (n >= N) return;
  const uint hd = lane >> 3;
  const float adst = a_dst[n * 8 + hd];
  const int degt = cnt[n];
  const int deg = degt < ELL_CAP ? degt : ELL_CAP;
  const uint* hu = (const uint*)hb;
  const ushort* row = ell + (size_t)n * ELL_CAP;

  float acc0 = 0.f, acc1 = 0.f, den = 0.f;
  const int full = deg & ~7;
  for (int e = 0; e < full; e += 8)
    gat_block<false>(hu, a_src, row, e, deg, hd, lane, adst, acc0, acc1, den);
  if (deg & 7)
    gat_block<true>(hu, a_src, row, full, deg, hd, lane, adst, acc0, acc1, den);

  {
    int novf = *ovfc;                        // ~always 0; one broadcast load
    if (novf > 0) {
      novf = novf < OVF_CAP ? novf : OVF_CAP;
      for (int q = 0; q < novf; ++q) {
        int2 pr = ovf[q];
        if (pr.x == n) {
          uint s = (uint)pr.y;
          float a = a_src[s * 8u + hd] + adst;
          a = a > 0.f ? a : 0.2f * a;
          float p = __expf(a);
          uint u = hu[(s << 6) | lane];
          acc0 = fmaf(p, bf2f_lo(u), acc0);
          acc1 = fmaf(p, bf2f_hi(u), acc1);
          den += p;
        }
      }
    }
  }
  float r = 1.0f / (den + 1e-16f);
  float2 bv = ((const float2*)bias)[lane];
  float2 xv = ((const float2*)x)[(size_t)n * 64 + lane];
  float o0 = fmaf(acc0, r, bv.x + xv.x);
  float o1 = fmaf(acc1, r, bv.y + xv.y);

  float s1 = o0 + o1;
  float s2 = o0 * o0 + o1 * o1;
#pragma unroll
  for (int off = 32; off > 0; off >>= 1) {
    s1 += __shfl_xor(s1, off);
    s2 += __shfl_xor(s2, off);
  }
  float mean = s1 * (1.0f / 128.0f);
  float var = s2 * (1.0f / 128.0f) - mean * mean;
  var = var < 0.f ? 0.f : var;
  float rstd = rsqrtf(var + 1e-5f);
  float2 gv = ((const float2*)gamma)[lane];
  float2 bt = ((const float2*)beta)[lane];
  float2 ov;
  ov.x = (o0 - mean) * rstd * gv.x + bt.x;
  ov.y = (o1 - mean) * rstd * gv.y + bt.y;
  ((float2*)out)[(size_t)n * 64 + lane] = ov;
}

// ---------------- launch ----------------
extern "C" void kernel_launch(void* const* d_in, const int* in_sizes, int n_in,
                              void* d_out, int out_size, void* d_ws, size_t ws_size,
                              hipStream_t stream) {
  const float* x       = (const float*)d_in[0];
  const int*   ei      = (const int*)d_in[1];
  const float* W       = (const float*)d_in[2];
  const float* att_src = (const float*)d_in[3];
  const float* att_dst = (const float*)d_in[4];
  const float* bias    = (const float*)d_in[5];
  const float* gamma   = (const float*)d_in[6];
  const float* beta    = (const float*)d_in[7];
  float* out = (float*)d_out;

  char* ws = (char*)d_ws;
  ushort* hb   = (ushort*)(ws + OFF_HB);
  float* a_src = (float*)(ws + OFF_ASRC);
  float* a_dst = (float*)(ws + OFF_ADST);
  int* cnt   = (int*)(ws + OFF_CNT);
  int* gcnt  = (int*)(ws + OFF_GCNT);
  int* ovfc  = (int*)(ws + OFF_OVFC);
  ushort* ell = (ushort*)(ws + OFF_ELL);
  uint* bkt  = (uint*)(ws + OFF_BKT);
  int2* ovf  = (int2*)(ws + OFF_OVF);
  char* Wt   = ws + OFF_WT;

  const int* srcIdx = ei;
  const int* dstIdx = ei + N_EDGES;

  hipMemsetAsync(ws + OFF_GCNT, 0, (NBKT + 1) * 4, stream);  // gcnt + ovfc
  k_binprep<<<NBKT + PREP_BLKS, 256, 0, stream>>>(srcIdx, dstIdx, gcnt, bkt, ovfc, ovf,
                                                  W, att_src, att_dst, Wt, N_EDGES);
  k_gemmbuild<<<NGEMM + NBKT, 256, 0, stream>>>(x, Wt, hb, a_src, a_dst,
                                                bkt, gcnt, cnt, ell, ovfc, ovf, N_NODES);
  k_gat<<<(N_NODES + 3) / 4, 256, 0, stream>>>(hb, a_src, a_dst, cnt, ell, ovfc, ovf, x, bias, gamma, beta, out, N_NODES);
}